// Round 13
// baseline (1947.000 us; speedup 1.0000x reference)
//
#include <hip/hip_runtime.h>
#include <hip/hip_bf16.h>

#define BS 8
#define V0 2048
#define V1N 512
#define V2N 128

typedef unsigned short ushort_t;
typedef __attribute__((ext_vector_type(8))) short bf16x8;
typedef __attribute__((ext_vector_type(4))) float f32x4;

#define KP1 1472       // 1424 real + zero pad to 64-multiple (BK=64)
#define PREP_BLKS 8193
#define GRID_BLKS 512  // == 2 blocks/CU × 256 CUs; co-residency guaranteed by
                       // __launch_bounds__(256,2) + 18.4KB LDS (≤2/CU fits)

// ---------------------------------------------------------------------------
// helpers
// ---------------------------------------------------------------------------
__device__ __forceinline__ void tf2x32(unsigned k0, unsigned k1,
                                       unsigned x0, unsigned x1,
                                       unsigned &o0, unsigned &o1) {
  unsigned ks2 = k0 ^ k1 ^ 0x1BD11BDAu;
  x0 += k0; x1 += k1;
#define RR(r) { x0 += x1; x1 = (x1 << (r)) | (x1 >> (32 - (r))); x1 ^= x0; }
  RR(13) RR(15) RR(26) RR(6)   x0 += k1;  x1 += ks2 + 1u;
  RR(17) RR(29) RR(16) RR(24)  x0 += ks2; x1 += k0 + 2u;
  RR(13) RR(15) RR(26) RR(6)   x0 += k0;  x1 += k1 + 3u;
  RR(17) RR(29) RR(16) RR(24)  x0 += k1;  x1 += ks2 + 4u;
  RR(13) RR(15) RR(26) RR(6)   x0 += ks2; x1 += k0 + 5u;
#undef RR
  o0 = x0; o1 = x1;
}

__device__ __forceinline__ ushort_t f2bf(float f) {
  unsigned u = __float_as_uint(f);
  u += 0x7FFFu + ((u >> 16) & 1u);
  return (ushort_t)(u >> 16);
}

__device__ __forceinline__ float sqdist_f32(float cx, float cy, float cz,
                                            const float* p) {
  float dx = __fsub_rn(cx, p[0]);
  float dy = __fsub_rn(cy, p[1]);
  float dz = __fsub_rn(cz, p[2]);
  return __fadd_rn(__fadd_rn(__fmul_rn(dx, dx), __fmul_rn(dy, dy)),
                   __fmul_rn(dz, dz));
}

__device__ __forceinline__ void dirn(const float* base, int v, int nb,
                                     float& ox, float& oy, float& oz) {
  float dx = __fsub_rn(base[nb * 3 + 0], base[v * 3 + 0]);
  float dy = __fsub_rn(base[nb * 3 + 1], base[v * 3 + 1]);
  float dz = __fsub_rn(base[nb * 3 + 2], base[v * 3 + 2]);
  float s2 = __fadd_rn(__fadd_rn(__fmul_rn(dx, dx), __fmul_rn(dy, dy)),
                       __fmul_rn(dz, dz));
  float nrm = fmaxf(__fsqrt_rn(s2), 1e-12f);
  ox = __fdiv_rn(dx, nrm); oy = __fdiv_rn(dy, nrm); oz = __fdiv_rn(dz, nrm);
}

__device__ __forceinline__ void norm_col(const float* d, int k,
                                         float& ox, float& oy, float& oz) {
  float x = d[k], y = d[32 + k], z = d[64 + k];
  float s2 = __fadd_rn(__fadd_rn(__fmul_rn(x, x), __fmul_rn(y, y)),
                       __fmul_rn(z, z));
  float nrm = fmaxf(__fsqrt_rn(s2), 1e-12f);
  ox = __fdiv_rn(x, nrm); oy = __fdiv_rn(y, nrm); oz = __fdiv_rn(z, nrm);
}

// ---------------------------------------------------------------------------
// manual grid barrier: one-shot per-phase counters (memset to 0 per call).
// release: __syncthreads + __threadfence before arrival (agent scope);
// acquire: spin-load AGENT-acquire + trailing __threadfence. Safe across
// non-coherent per-XCD L2s (G16); cannot deadlock given co-residency.
// ---------------------------------------------------------------------------
__device__ __forceinline__ void grid_barrier(int* bar, int ph) {
  __syncthreads();
  if (threadIdx.x == 0) {
    __threadfence();
    int prev = __hip_atomic_fetch_add(&bar[ph], 1, __ATOMIC_ACQ_REL,
                                      __HIP_MEMORY_SCOPE_AGENT);
    if (prev + 1 < GRID_BLKS) {
      while (__hip_atomic_load(&bar[ph], __ATOMIC_ACQUIRE,
                               __HIP_MEMORY_SCOPE_AGENT) < GRID_BLKS)
        __builtin_amdgcn_s_sleep(8);
    }
  }
  __syncthreads();
  __threadfence();
}

// ---------------------------------------------------------------------------
// shared-memory union for the mega kernel (max member ≈ 18.4 KB)
// ---------------------------------------------------------------------------
union SharedU {
  unsigned rank_sb[2048];
  struct { int a1[2048]; int a2[2048]; } comp;
  struct { float sdir[3][32]; float sdn[8][32][3]; float sfm[8][32]; } cs;
  struct { float sdir[3][32]; float sdn[8][32][3]; int sidx[8][32];
           float sfm[8][256]; } ca;
  struct { float spts[512 * 3]; float sdir[3][32]; float sdn[8][32][3];
           int sni[8][32]; float sfm[8][256]; } cq;
  struct { float spf[4][192]; } pl;
  struct { unsigned long long red[256]; int sn1, sn2; } fr;
};

struct MegaArgs {
  const float* vertices; const float* onehot; const float* d0;
  const float* w[8]; const float* bb[8]; const float* dd[8];  // 1..7 used
  const float* cw1; const float* cw2; const float* cw3; const float* cb3;
  int* bar;
  int* rank; int* perm1; int* perm2;
  int* ni1; int* ni2; int* ni3;
  float* fm2; float* fm5; float* fm7; float* fbuf;
  float* v1; float* v2; float* fglob;
  ushort_t* fuse_b; ushort_t* cw1b; ushort_t* cw2b; ushort_t* cw3b;
  float* cb3p;
};

// ---------------------------------------------------------------------------
// phase bodies (verbatim R11 kernels, blockIdx.x → vb)
// ---------------------------------------------------------------------------
__device__ void ph_misc1(SharedU& su, int vb, int tid, const MegaArgs& a) {
  if (vb < 18) {
    unsigned* sb = su.rank_sb;
    int seg, segfirst, n, base;
    if (vb < 8)       { seg = 0; segfirst = 0;  n = 2048; base = 0; }
    else if (vb < 16) { seg = 1; segfirst = 8;  n = 2048; base = 2048; }
    else              { seg = 2; segfirst = 16; n = 512;  base = 4096; }
    unsigned k0, k1, nk0, nk1, sk0, sk1;
    if (seg == 0) {
      tf2x32(0u, 42u, 0u, 1u, k0, k1);
      tf2x32(k0, k1, 0u, 1u, sk0, sk1);
    } else if (seg == 1) {
      tf2x32(0u, 42u, 0u, 1u, k0, k1);
      tf2x32(k0, k1, 0u, 0u, nk0, nk1);
      tf2x32(nk0, nk1, 0u, 1u, sk0, sk1);
    } else {
      tf2x32(0u, 42u, 0u, 2u, k0, k1);
      tf2x32(k0, k1, 0u, 1u, sk0, sk1);
    }
    for (int i = tid; i < n; i += 256) {
      unsigned o0, o1;
      tf2x32(sk0, sk1, 0u, (unsigned)i, o0, o1);
      sb[i] = o0 ^ o1;
    }
    __syncthreads();
    int tt = (vb - segfirst) * 256 + tid;
    unsigned bt = sb[tt];
    int cnt = 0;
#pragma unroll 8
    for (int s = 0; s < n; ++s) {
      unsigned bs2 = sb[s];
      cnt += (bs2 < bt) || (bs2 == bt && s < tt);
    }
    a.rank[base + tt] = cnt;
  } else if (vb < 18 + PREP_BLKS) {
    long long t = (long long)(vb - 18) * 256 + tid;
    const long long N1 = 1024LL * KP1, N2 = 512LL * 1024, N3 = 128LL * 512;
    if (t < N1) {
      int k = (int)(t % KP1);
      int n = (int)(t / KP1);
      a.cw1b[t] = f2bf(k < 1424 ? a.cw1[(size_t)n * 1424 + k] : 0.f);
    } else if (t < N1 + N2) {
      long long u = t - N1;
      a.cw2b[u] = f2bf(a.cw2[u]);
    } else if (t < N1 + N2 + N3) {
      long long u = t - N1 - N2;
      int k = (int)(u & 511);
      int n = (int)(u >> 9);
      a.cw3b[u] = f2bf(n < 50 ? a.cw3[(size_t)n * 512 + k] : 0.f);
    } else if (t < N1 + N2 + N3 + 128) {
      int u = (int)(t - N1 - N2 - N3);
      a.cb3p[u] = u < 50 ? a.cb3[u] : 0.f;
    }
  } else {
    int bq = vb - 18 - PREP_BLKS;
    int wid = bq * 4 + (tid >> 6);
    int lane = tid & 63;
    int b = wid >> 11, i = wid & 2047;
    const float* base = a.vertices + (size_t)b * V0 * 3;
    float cx = base[i * 3], cy = base[i * 3 + 1], cz = base[i * 3 + 2];
    int cnt = 0, idx0 = 0;
    for (int j0 = 0; j0 < V0; j0 += 64) {
      int j = j0 + lane;
      float d2 = sqdist_f32(cx, cy, cz, base + (size_t)j * 3);
      bool in = (d2 <= 0.0625f);
      unsigned long long mask = __ballot(in);
      if (cnt == 0 && mask) idx0 = j0 + __builtin_ctzll(mask);
      if (in) {
        int rk = cnt + __popcll(mask & ((1ull << lane) - 1ull));
        if (rk < 32) a.ni1[(size_t)wid * 32 + rk] = j;
      }
      cnt += __popcll(mask);
      if (cnt >= 32) break;
    }
    for (int s = cnt + lane; s < 32; s += 64)
      a.ni1[(size_t)wid * 32 + s] = idx0;
  }
}

__device__ void ph_misc2(SharedU& su, int vb, int tid, const MegaArgs& a) {
  if (vb == 0) {
    int* a1 = su.comp.a1;
    int* a2 = su.comp.a2;
    for (int i = tid; i < 2048; i += 256) a1[a.rank[i]] = i;
    __syncthreads();
    for (int i = tid; i < 2048; i += 256) a2[a.rank[2048 + i]] = a1[i];
    __syncthreads();
    for (int i = tid; i < 512; i += 256) a.perm1[i] = a2[i];
    for (int i = tid; i < 512; i += 256) a1[a.rank[4096 + i]] = i;
    __syncthreads();
    for (int i = tid; i < 128; i += 256) a.perm2[i] = a1[i];
    return;
  }
  auto& s = su.cs;
  if (tid < 32) {
    float x, y, z; norm_col(a.d0, tid, x, y, z);
    s.sdir[0][tid] = x; s.sdir[1][tid] = y; s.sdir[2][tid] = z;
  }
  int vloc = tid >> 5, k = tid & 31;
  size_t bvg = (size_t)(vb - 1) * 8 + vloc;
  int b = (int)(bvg >> 11), v = (int)(bvg & 2047);
  const float* base = a.vertices + (size_t)b * V0 * 3;
  int nb = a.ni1[bvg * 32 + k];
  float x, y, z; dirn(base, v, nb, x, y, z);
  s.sdn[vloc][k][0] = x; s.sdn[vloc][k][1] = y; s.sdn[vloc][k][2] = z;
  __syncthreads();
  float m = 0.f;
  for (int n = 0; n < 32; ++n) {
    float d = s.sdn[vloc][n][0] * s.sdir[0][k] + s.sdn[vloc][n][1] * s.sdir[1][k] +
              s.sdn[vloc][n][2] * s.sdir[2][k];
    m = fmaxf(m, fmaxf(d, 0.f));
  }
  a.fm2[bvg * 96 + k] = m;
  s.sfm[vloc][k] = m;
  __syncthreads();
  float a1v = a.bb[1][k], a2v = a.bb[1][k + 32];
  for (int c = 0; c < 32; ++c) {
    float vv = s.sfm[vloc][c];
    a1v += vv * a.w[1][c * 64 + k];
    a2v += vv * a.w[1][c * 64 + k + 32];
  }
  a.fbuf[bvg * 64 + k] = a1v;
  a.fbuf[bvg * 64 + k + 32] = a2v;
}

__device__ void ph_conv_act(SharedU& su, int vb, int tid, const float* pts,
                            const float* dd, const int* ni, const float* f,
                            float* out, int Nv, int ldout, int colofs,
                            const float* wn, const float* bn, float* fn) {
  auto& s = su.ca;
  if (tid < 32) {
    float x, y, z; norm_col(dd, tid, x, y, z);
    s.sdir[0][tid] = x; s.sdir[1][tid] = y; s.sdir[2][tid] = z;
  }
  int vloc = tid >> 5, k = tid & 31;
  size_t bvg = (size_t)vb * 8 + vloc;
  int b = (int)(bvg / Nv), v = (int)(bvg % Nv);
  const float* base = pts + (size_t)b * Nv * 3;
  int nb = ni[bvg * 32 + k];
  float x, y, z; dirn(base, v, nb, x, y, z);
  s.sdn[vloc][k][0] = x; s.sdn[vloc][k][1] = y; s.sdn[vloc][k][2] = z;
  s.sidx[vloc][k] = nb;
  __syncthreads();
  float m = -INFINITY;
  size_t fb = (size_t)b * Nv * 64;
  for (int n = 0; n < 32; ++n) {
    float th = fmaxf(s.sdn[vloc][n][0] * s.sdir[0][k] + s.sdn[vloc][n][1] * s.sdir[1][k] +
                     s.sdn[vloc][n][2] * s.sdir[2][k], 0.f);
    float sup = f[fb + (size_t)s.sidx[vloc][n] * 64 + 32 + k];
    m = fmaxf(m, th * sup);
  }
  float center = f[bvg * 64 + k];
  float res = fmaxf(center + m, 0.f);
  out[bvg * ldout + colofs + k] = res;
  if (wn) {
    size_t rowbase = (size_t)vb * 8;
#pragma unroll 1
    for (int r = 0; r < 8; ++r)
      if (tid < colofs) s.sfm[r][tid] = out[(rowbase + r) * ldout + tid];
    s.sfm[vloc][colofs + k] = res;
    __syncthreads();
    int cin = colofs + 32;
    float a1v = bn[k], a2v = bn[k + 32];
    for (int c = 0; c < cin; ++c) {
      float vv = s.sfm[vloc][c];
      a1v += vv * wn[c * 64 + k];
      a2v += vv * wn[c * 64 + k + 32];
    }
    fn[bvg * 64 + k] = a1v;
    fn[bvg * 64 + k + 32] = a2v;
  }
}

__device__ void ph_conv_qbp(SharedU& su, int vb, int tid, const float* pts,
                            int Nv, float rrq, const float* dd, int* ni_out,
                            const float* f, float* out, int ldout, int colofs,
                            const float* wn, const float* bn, float* fn) {
  auto& s = su.cq;
  int b = (vb * 8) / Nv;
  int vbase = (vb * 8) % Nv;
  const float* gp = pts + (size_t)b * Nv * 3;
  for (int i = tid; i < Nv * 3; i += 256) s.spts[i] = gp[i];
  if (tid < 32) {
    float x, y, z; norm_col(dd, tid, x, y, z);
    s.sdir[0][tid] = x; s.sdir[1][tid] = y; s.sdir[2][tid] = z;
  }
  __syncthreads();
  int lane = tid & 63, wv = tid >> 6;
  for (int rep = 0; rep < 2; ++rep) {
    int vl = wv * 2 + rep;
    int v = vbase + vl;
    float cx = s.spts[v * 3], cy = s.spts[v * 3 + 1], cz = s.spts[v * 3 + 2];
    int cnt = 0, idx0 = 0;
    for (int j0 = 0; j0 < Nv; j0 += 64) {
      int j = j0 + lane;
      float d2 = sqdist_f32(cx, cy, cz, s.spts + (size_t)j * 3);
      bool in = (d2 <= rrq);
      unsigned long long mask = __ballot(in);
      if (cnt == 0 && mask) idx0 = j0 + __builtin_ctzll(mask);
      if (in) {
        int rk = cnt + __popcll(mask & ((1ull << lane) - 1ull));
        if (rk < 32) s.sni[vl][rk] = j;
      }
      cnt += __popcll(mask);
      if (cnt >= 32) break;
    }
    for (int q = cnt + lane; q < 32; q += 64) s.sni[vl][q] = idx0;
  }
  __syncthreads();
  ni_out[(size_t)(vb * 8) * 32 + tid] = s.sni[tid >> 5][tid & 31];
  int vloc = tid >> 5, k = tid & 31;
  size_t bvg = (size_t)vb * 8 + vloc;
  int v = vbase + vloc;
  int nb = s.sni[vloc][k];
  float x, y, z; dirn(s.spts, v, nb, x, y, z);
  s.sdn[vloc][k][0] = x; s.sdn[vloc][k][1] = y; s.sdn[vloc][k][2] = z;
  __syncthreads();
  float m = -INFINITY;
  size_t fb = (size_t)b * Nv * 64;
  for (int n = 0; n < 32; ++n) {
    float th = fmaxf(s.sdn[vloc][n][0] * s.sdir[0][k] + s.sdn[vloc][n][1] * s.sdir[1][k] +
                     s.sdn[vloc][n][2] * s.sdir[2][k], 0.f);
    float sup = f[fb + (size_t)s.sni[vloc][n] * 64 + 32 + k];
    m = fmaxf(m, th * sup);
  }
  float center = f[bvg * 64 + k];
  float res = fmaxf(center + m, 0.f);
  out[bvg * ldout + colofs + k] = res;
  size_t rowbase = (size_t)vb * 8;
#pragma unroll 1
  for (int r = 0; r < 8; ++r)
    if (tid < colofs) s.sfm[r][tid] = out[(rowbase + r) * ldout + tid];
  s.sfm[vloc][colofs + k] = res;
  __syncthreads();
  int cin = colofs + 32;
  float a1v = bn[k], a2v = bn[k + 32];
  for (int c = 0; c < cin; ++c) {
    float vv = s.sfm[vloc][c];
    a1v += vv * wn[c * 64 + k];
    a2v += vv * wn[c * 64 + k + 32];
  }
  fn[bvg * 64 + k] = a1v;
  fn[bvg * 64 + k + 32] = a2v;
}

__device__ void ph_pool(SharedU& su, int vb, int tid, const float* pts_in,
                        const float* fm_in, int ld_in, int C, int Nv_in,
                        const int* perm, int Nv_out, float rr, float* pts_out,
                        float* fm_out, int ld_out, const float* wn,
                        const float* bn, float* fn) {
  auto& s = su.pl;
  int wv = tid >> 6;
  int lane = tid & 63;
  int wid = vb * 4 + wv;
  int b = wid / Nv_out, pp = wid - b * Nv_out;
  int v = perm[pp];
  const float* base = pts_in + (size_t)b * Nv_in * 3;
  float cx = base[v * 3], cy = base[v * 3 + 1], cz = base[v * 3 + 2];
  int nb[4]; int cnt = 0;
  for (int j0 = 0; j0 < Nv_in && cnt < 4; j0 += 64) {
    int j = j0 + lane;
    float d2 = sqdist_f32(cx, cy, cz, base + (size_t)j * 3);
    unsigned long long mask = __ballot(d2 <= rr);
    while (mask && cnt < 4) {
      int bp = __builtin_ctzll(mask);
      mask &= mask - 1;
      nb[cnt++] = j0 + bp;
    }
  }
  for (int q = cnt; q < 4; ++q) nb[q] = nb[0];
  if (lane < 3) pts_out[(size_t)wid * 3 + lane] = base[v * 3 + lane];
  size_t inrow = (size_t)b * Nv_in;
  size_t outrow = (size_t)wid * ld_out;
  for (int c = lane; c < C; c += 64) {
    float m = fm_in[(inrow + nb[0]) * ld_in + c];
    m = fmaxf(m, fm_in[(inrow + nb[1]) * ld_in + c]);
    m = fmaxf(m, fm_in[(inrow + nb[2]) * ld_in + c]);
    m = fmaxf(m, fm_in[(inrow + nb[3]) * ld_in + c]);
    fm_out[outrow + c] = m;
    s.spf[wv][c] = m;
  }
  __syncthreads();
  int o = tid & 63, w_ = tid >> 6;
  int wid0 = vb * 4 + w_;
  float aa = bn[o];
  for (int c = 0; c < C; ++c) aa += s.spf[w_][c] * wn[c * 64 + o];
  fn[(size_t)wid0 * 64 + o] = aa;
}

__device__ void ph_gmax(int vb, int tid, const float* fm, float* out) {
  int t = vb * 256 + tid;
  if (t < BS * 256) {
    int b = t >> 8, c = t & 255;
    float m = -INFINITY;
    for (int v = 0; v < V2N; ++v)
      m = fmaxf(m, fm[((size_t)b * V2N + v) * 256 + c]);
    out[t] = m;
  }
}

__device__ void ph_fuse(SharedU& su, int vb, int tid, const MegaArgs& a) {
  auto& s = su.fr;
  int bv = vb;
  int b = bv >> 11;
  float cx = a.vertices[(size_t)bv * 3 + 0];
  float cy = a.vertices[(size_t)bv * 3 + 1];
  float cz = a.vertices[(size_t)bv * 3 + 2];
  unsigned long long best = ~0ull;
  const float* sb = a.v1 + (size_t)b * V1N * 3;
  for (int j = tid; j < V1N; j += 256) {
    float d2 = sqdist_f32(cx, cy, cz, sb + (size_t)j * 3);
    unsigned long long key =
        (((unsigned long long)__float_as_uint(d2)) << 32) | (unsigned)j;
    best = best < key ? best : key;
  }
  s.red[tid] = best;
  __syncthreads();
  for (int st = 128; st > 0; st >>= 1) {
    if (tid < st) s.red[tid] = s.red[tid] < s.red[tid + st] ? s.red[tid] : s.red[tid + st];
    __syncthreads();
  }
  if (tid == 0) s.sn1 = (int)(s.red[0] & 0xffffffffu);
  __syncthreads();
  best = ~0ull;
  sb = a.v2 + (size_t)b * V2N * 3;
  for (int j = tid; j < V2N; j += 256) {
    float d2 = sqdist_f32(cx, cy, cz, sb + (size_t)j * 3);
    unsigned long long key =
        (((unsigned long long)__float_as_uint(d2)) << 32) | (unsigned)j;
    best = best < key ? best : key;
  }
  s.red[tid] = best;
  __syncthreads();
  for (int st = 128; st > 0; st >>= 1) {
    if (tid < st) s.red[tid] = s.red[tid] < s.red[tid + st] ? s.red[tid] : s.red[tid + st];
    __syncthreads();
  }
  if (tid == 0) s.sn2 = (int)(s.red[0] & 0xffffffffu);
  __syncthreads();
  const float* r2 = a.fm2 + (size_t)bv * 96;
  const float* r5 = a.fm5 + ((size_t)b * V1N + s.sn1) * 192;
  const float* r7 = a.fm7 + ((size_t)b * V2N + s.sn2) * 256;
  const float* rg = a.fglob + b * 256;
  const float* roh = a.onehot + b * 16;
  if (tid < KP1 / 8) {
    int c = tid * 8;
    const float* src = nullptr;
    if (c < 192) {
      int cc = (c < 32) ? c : (c < 96 ? c - 32 : c - 96);
      src = r2 + cc;
    } else if (c < 672) {
      int cc = (c < 320) ? c - 192 : (c < 480 ? c - 320 : c - 480);
      src = r5 + cc;
    } else if (c < 1152) {
      int cc = (c < 896) ? c - 672 : c - 896;
      src = r7 + cc;
    } else if (c < 1408) {
      src = rg + (c - 1152);
    } else if (c < 1424) {
      src = roh + (c - 1408);
    }
    float4 lo = make_float4(0.f, 0.f, 0.f, 0.f), hi = lo;
    if (src) { lo = *(const float4*)src; hi = *(const float4*)(src + 4); }
    bf16x8 o;
    o[0] = (short)f2bf(lo.x); o[1] = (short)f2bf(lo.y);
    o[2] = (short)f2bf(lo.z); o[3] = (short)f2bf(lo.w);
    o[4] = (short)f2bf(hi.x); o[5] = (short)f2bf(hi.y);
    o[6] = (short)f2bf(hi.z); o[7] = (short)f2bf(hi.w);
    *(bf16x8*)(a.fuse_b + (size_t)bv * KP1 + c) = o;
  }
}

// ---------------------------------------------------------------------------
// mega kernel: the whole preamble as 13 phases, manual grid barriers between
// ---------------------------------------------------------------------------
__global__ __launch_bounds__(256, 2) void mega_kernel(MegaArgs a) {
  __shared__ SharedU su;
  int tid = threadIdx.x;
  const float rr1 = 0.0625f;
  const float rr2 = (float)(0.39 * 0.39);
  const float rr3 = (float)(0.63 * 0.63);

#define PHASE(PH, NVB, BODY)                                   \
  for (int vb = blockIdx.x; vb < (NVB); vb += GRID_BLKS) {     \
    BODY;                                                      \
    __syncthreads();                                           \
  }                                                            \
  grid_barrier(a.bar, PH);

  PHASE(0, 18 + PREP_BLKS + 4096, ph_misc1(su, vb, tid, a))
  PHASE(1, 2049, ph_misc2(su, vb, tid, a))
  PHASE(2, 2048, ph_conv_act(su, vb, tid, a.vertices, a.dd[1], a.ni1, a.fbuf,
                             a.fm2, V0, 96, 32, a.w[2], a.bb[2], a.fbuf))
  PHASE(3, 2048, ph_conv_act(su, vb, tid, a.vertices, a.dd[2], a.ni1, a.fbuf,
                             a.fm2, V0, 96, 64, nullptr, nullptr, nullptr))
  PHASE(4, 1024, ph_pool(su, vb, tid, a.vertices, a.fm2, 96, 96, V0, a.perm1,
                         V1N, rr1, a.v1, a.fm5, 192, a.w[3], a.bb[3], a.fbuf))
  PHASE(5, 512, ph_conv_qbp(su, vb, tid, a.v1, V1N, rr2, a.dd[3], a.ni2,
                            a.fbuf, a.fm5, 192, 96, a.w[4], a.bb[4], a.fbuf))
  PHASE(6, 512, ph_conv_act(su, vb, tid, a.v1, a.dd[4], a.ni2, a.fbuf, a.fm5,
                            V1N, 192, 128, a.w[5], a.bb[5], a.fbuf))
  PHASE(7, 512, ph_conv_act(su, vb, tid, a.v1, a.dd[5], a.ni2, a.fbuf, a.fm5,
                            V1N, 192, 160, nullptr, nullptr, nullptr))
  PHASE(8, 256, ph_pool(su, vb, tid, a.v1, a.fm5, 192, 192, V1N, a.perm2, V2N,
                        rr2, a.v2, a.fm7, 256, a.w[6], a.bb[6], a.fbuf))
  PHASE(9, 128, ph_conv_qbp(su, vb, tid, a.v2, V2N, rr3, a.dd[6], a.ni3,
                            a.fbuf, a.fm7, 256, 192, a.w[7], a.bb[7], a.fbuf))
  PHASE(10, 128, ph_conv_act(su, vb, tid, a.v2, a.dd[7], a.ni3, a.fbuf, a.fm7,
                             V2N, 256, 224, nullptr, nullptr, nullptr))
  PHASE(11, 8, ph_gmax(vb, tid, a.fm7, a.fglob))
  // last phase: no trailing barrier (kernel completion orders with gemms)
  for (int vb = blockIdx.x; vb < BS * V0; vb += GRID_BLKS) {
    ph_fuse(su, vb, tid, a);
    __syncthreads();
  }
#undef PHASE
}

// ---------------------------------------------------------------------------
// bf16 MFMA GEMM — BK=64 + XCD swizzle + XOR-8 chunk swizzle (R11: 0 bank
// conflicts, verified). Unchanged.
// ---------------------------------------------------------------------------
typedef const __attribute__((address_space(1))) unsigned int gas_u32;
typedef __attribute__((address_space(3))) unsigned int las_u32;

__global__ __launch_bounds__(256) void gemm_mfma_nt(
    const ushort_t* __restrict__ A, const ushort_t* __restrict__ B,
    const float* __restrict__ bias, ushort_t* __restrict__ Cb,
    float* __restrict__ Cf, int K, int ldc, int nvalid, int mode) {
  __shared__ ushort_t As[128 * 64];
  __shared__ ushort_t Bs[128 * 64];
  int tid = threadIdx.x;
  int lane = tid & 63, w = tid >> 6;
  int wm = (w >> 1) * 64, wn = (w & 1) * 64;
  int nb = gridDim.x;
  int flat = blockIdx.x + nb * blockIdx.y;
  int xcd = flat & 7, slot = flat >> 3;
  int nidx = slot % nb;
  int mband = xcd + 8 * (slot / nb);
  int bm = mband * 128, bn = nidx * 128;
  f32x4 acc[4][4];
#pragma unroll
  for (int i = 0; i < 4; ++i)
#pragma unroll
    for (int j = 0; j < 4; ++j) acc[i][j] = (f32x4){0.f, 0.f, 0.f, 0.f};

  const ushort_t* gA[4];
  const ushort_t* gB[4];
  ushort_t* lA[4];
  ushort_t* lB[4];
  int rsub = lane >> 3;
  int scol = ((lane & 7) ^ rsub) * 8;        // XOR-8 swizzled global chunk
#pragma unroll
  for (int g = 0; g < 4; ++g) {
    int r = w * 32 + g * 8 + rsub;
    gA[g] = A + (size_t)(bm + r) * K + scol;
    gB[g] = B + (size_t)(bn + r) * K + scol;
    lA[g] = As + (w * 32 + g * 8) * 64;
    lB[g] = Bs + (w * 32 + g * 8) * 64;
  }
  int rA = lane & 15, q = lane >> 4;
  int r7 = rA & 7;

  for (int k0 = 0; k0 < K; k0 += 64) {
#pragma unroll
    for (int g = 0; g < 4; ++g)
      __builtin_amdgcn_global_load_lds((gas_u32*)(gA[g] + k0), (las_u32*)lA[g],
                                       16, 0, 0);
#pragma unroll
    for (int g = 0; g < 4; ++g)
      __builtin_amdgcn_global_load_lds((gas_u32*)(gB[g] + k0), (las_u32*)lB[g],
                                       16, 0, 0);
    __syncthreads();
#pragma unroll
    for (int s = 0; s < 2; ++s) {
      int pc = ((s * 4 + q) ^ r7) * 8;        // physical chunk offset
      bf16x8 af[4], bfr[4];
#pragma unroll
      for (int i = 0; i < 4; ++i)
        af[i] = *(const bf16x8*)(As + (wm + i * 16 + rA) * 64 + pc);
#pragma unroll
      for (int j = 0; j < 4; ++j)
        bfr[j] = *(const bf16x8*)(Bs + (wn + j * 16 + rA) * 64 + pc);
#pragma unroll
      for (int i = 0; i < 4; ++i)
#pragma unroll
        for (int j = 0; j < 4; ++j)
          acc[i][j] = __builtin_amdgcn_mfma_f32_16x16x32_bf16(af[i], bfr[j],
                                                              acc[i][j], 0, 0, 0);
    }
    __syncthreads();
  }

  int rowq = (lane >> 4) * 4;
  int coll = lane & 15;
#pragma unroll
  for (int i = 0; i < 4; ++i) {
#pragma unroll
    for (int j = 0; j < 4; ++j) {
      int col = bn + wn + j * 16 + coll;
      float bi = bias[col];
#pragma unroll
      for (int r = 0; r < 4; ++r) {
        int row = bm + wm + i * 16 + rowq + r;
        float v = acc[i][j][r] + bi;
        if (mode == 0) {
          Cb[(size_t)row * ldc + col] = f2bf(fmaxf(v, 0.f));
        } else if (col < nvalid) {
          Cf[(size_t)row * ldc + col] = v;
        }
      }
    }
  }
}

// ---------------------------------------------------------------------------
extern "C" void kernel_launch(void* const* d_in, const int* in_sizes, int n_in,
                              void* d_out, int out_size, void* d_ws,
                              size_t ws_size, hipStream_t stream) {
  MegaArgs a;
  a.vertices = (const float*)d_in[0];
  a.onehot = (const float*)d_in[1];
  a.d0 = (const float*)d_in[2];
  for (int i = 1; i <= 7; ++i) {
    a.w[i] = (const float*)d_in[3 * i];
    a.bb[i] = (const float*)d_in[3 * i + 1];
    a.dd[i] = (const float*)d_in[3 * i + 2];
  }
  a.w[0] = a.bb[0] = a.dd[0] = nullptr;
  a.cw1 = (const float*)d_in[24];
  const float* cb1 = (const float*)d_in[25];
  a.cw2 = (const float*)d_in[26];
  const float* cb2 = (const float*)d_in[27];
  a.cw3 = (const float*)d_in[28];
  a.cb3 = (const float*)d_in[29];
  float* out = (float*)d_out;

  char* wsp = (char*)d_ws;
  size_t off = 0;
  auto alloc = [&](size_t bytes) -> void* {
    void* p = wsp + off;
    off += (bytes + 255) & ~(size_t)255;
    return p;
  };
  const int M = BS * V0;  // 16384
  a.bar = (int*)alloc(16 * 4);
  a.rank = (int*)alloc(4608 * 4);
  a.perm1 = (int*)alloc(512 * 4);
  a.perm2 = (int*)alloc(128 * 4);
  a.ni1 = (int*)alloc((size_t)BS * V0 * 32 * 4);
  a.ni2 = (int*)alloc((size_t)BS * V1N * 32 * 4);
  a.ni3 = (int*)alloc((size_t)BS * V2N * 32 * 4);
  a.fm2 = (float*)alloc((size_t)BS * V0 * 96 * 4);
  a.fm5 = (float*)alloc((size_t)BS * V1N * 192 * 4);
  a.fm7 = (float*)alloc((size_t)BS * V2N * 256 * 4);
  a.fbuf = (float*)alloc((size_t)BS * V0 * 64 * 4);
  a.v1 = (float*)alloc((size_t)BS * V1N * 3 * 4);
  a.v2 = (float*)alloc((size_t)BS * V2N * 3 * 4);
  a.fglob = (float*)alloc((size_t)BS * 256 * 4);
  a.fuse_b = (ushort_t*)alloc((size_t)M * KP1 * 2);
  ushort_t* h1b = (ushort_t*)alloc((size_t)M * 1024 * 2);
  ushort_t* h2b = (ushort_t*)alloc((size_t)M * 512 * 2);
  a.cw1b = (ushort_t*)alloc((size_t)1024 * KP1 * 2);
  a.cw2b = (ushort_t*)alloc((size_t)512 * 1024 * 2);
  a.cw3b = (ushort_t*)alloc((size_t)128 * 512 * 2);
  a.cb3p = (float*)alloc(128 * 4);

  // zero the barrier counters (ws is re-poisoned to 0xAA before every launch)
  hipMemsetAsync(a.bar, 0, 16 * 4, stream);

  // 1 launch: entire preamble (13 phases, manual grid barriers)
  mega_kernel<<<GRID_BLKS, 256, 0, stream>>>(a);

  // 2-4: MLP head (bf16 MFMA, BK=64 + XOR-8 swizzle)
  gemm_mfma_nt<<<dim3(1024 / 128, M / 128), 256, 0, stream>>>(
      a.fuse_b, a.cw1b, cb1, h1b, nullptr, KP1, 1024, 1024, 0);
  gemm_mfma_nt<<<dim3(512 / 128, M / 128), 256, 0, stream>>>(
      h1b, a.cw2b, cb2, h2b, nullptr, 1024, 512, 512, 0);
  gemm_mfma_nt<<<dim3(1, M / 128), 256, 0, stream>>>(
      h2b, a.cw3b, a.cb3p, nullptr, out, 512, 50, 50, 1);
}

// Round 14
// 423.329 us; speedup vs baseline: 4.5993x; 4.5993x over previous
//
#include <hip/hip_runtime.h>
#include <hip/hip_bf16.h>

#define BS 8
#define V0 2048
#define V1N 512
#define V2N 128

typedef unsigned short ushort_t;
typedef __attribute__((ext_vector_type(8))) short bf16x8;
typedef __attribute__((ext_vector_type(4))) float f32x4;

// ---------------------------------------------------------------------------
// Threefry2x32 cipher (JAX partitionable mode — verified R4)
// ---------------------------------------------------------------------------
__device__ __forceinline__ void tf2x32(unsigned k0, unsigned k1,
                                       unsigned x0, unsigned x1,
                                       unsigned &o0, unsigned &o1) {
  unsigned ks2 = k0 ^ k1 ^ 0x1BD11BDAu;
  x0 += k0; x1 += k1;
#define RR(r) { x0 += x1; x1 = (x1 << (r)) | (x1 >> (32 - (r))); x1 ^= x0; }
  RR(13) RR(15) RR(26) RR(6)   x0 += k1;  x1 += ks2 + 1u;
  RR(17) RR(29) RR(16) RR(24)  x0 += ks2; x1 += k0 + 2u;
  RR(13) RR(15) RR(26) RR(6)   x0 += k0;  x1 += k1 + 3u;
  RR(17) RR(29) RR(16) RR(24)  x0 += k1;  x1 += ks2 + 4u;
  RR(13) RR(15) RR(26) RR(6)   x0 += ks2; x1 += k0 + 5u;
#undef RR
  o0 = x0; o1 = x1;
}

__device__ __forceinline__ ushort_t f2bf(float f) {
  unsigned u = __float_as_uint(f);
  u += 0x7FFFu + ((u >> 16) & 1u);
  return (ushort_t)(u >> 16);
}

__device__ __forceinline__ float sqdist_f32(float cx, float cy, float cz,
                                            const float* p) {
  float dx = __fsub_rn(cx, p[0]);
  float dy = __fsub_rn(cy, p[1]);
  float dz = __fsub_rn(cz, p[2]);
  return __fadd_rn(__fadd_rn(__fmul_rn(dx, dx), __fmul_rn(dy, dy)),
                   __fmul_rn(dz, dz));
}

#define KP1 1472   // 1424 real + zero pad to 64-multiple (BK=64)

// ---------------------------------------------------------------------------
// misc1: [0,18) threefry rank · [18,18+PREP_BLKS) weight prep · rest qbp lvl-1
// ---------------------------------------------------------------------------
#define PREP_BLKS 8193
__global__ __launch_bounds__(256) void misc1_kernel(
    int* __restrict__ rank, const float* __restrict__ cw1,
    const float* __restrict__ cw2, const float* __restrict__ cw3,
    const float* __restrict__ cb3, ushort_t* __restrict__ cw1b,
    ushort_t* __restrict__ cw2b, ushort_t* __restrict__ cw3b,
    float* __restrict__ cb3p, const float* __restrict__ pts,
    int* __restrict__ ni1) {
  int bid = blockIdx.x, tid = threadIdx.x;
  if (bid < 18) {
    __shared__ unsigned sb[2048];
    int seg, segfirst, n, base;
    if (bid < 8)       { seg = 0; segfirst = 0;  n = 2048; base = 0; }
    else if (bid < 16) { seg = 1; segfirst = 8;  n = 2048; base = 2048; }
    else               { seg = 2; segfirst = 16; n = 512;  base = 4096; }
    unsigned k0, k1, nk0, nk1, sk0, sk1;
    if (seg == 0) {
      tf2x32(0u, 42u, 0u, 1u, k0, k1);
      tf2x32(k0, k1, 0u, 1u, sk0, sk1);
    } else if (seg == 1) {
      tf2x32(0u, 42u, 0u, 1u, k0, k1);
      tf2x32(k0, k1, 0u, 0u, nk0, nk1);
      tf2x32(nk0, nk1, 0u, 1u, sk0, sk1);
    } else {
      tf2x32(0u, 42u, 0u, 2u, k0, k1);
      tf2x32(k0, k1, 0u, 1u, sk0, sk1);
    }
    for (int i = tid; i < n; i += 256) {
      unsigned o0, o1;
      tf2x32(sk0, sk1, 0u, (unsigned)i, o0, o1);
      sb[i] = o0 ^ o1;
    }
    __syncthreads();
    int tt = (bid - segfirst) * 256 + tid;
    unsigned bt = sb[tt];
    int cnt = 0;
#pragma unroll 8
    for (int s = 0; s < n; ++s) {
      unsigned bs = sb[s];
      cnt += (bs < bt) || (bs == bt && s < tt);
    }
    rank[base + tt] = cnt;
  } else if (bid < 18 + PREP_BLKS) {
    long long t = (long long)(bid - 18) * 256 + tid;
    const long long N1 = 1024LL * KP1, N2 = 512LL * 1024, N3 = 128LL * 512;
    if (t < N1) {
      int k = (int)(t % KP1);
      int n = (int)(t / KP1);
      cw1b[t] = f2bf(k < 1424 ? cw1[(size_t)n * 1424 + k] : 0.f);
    } else if (t < N1 + N2) {
      long long u = t - N1;
      cw2b[u] = f2bf(cw2[u]);
    } else if (t < N1 + N2 + N3) {
      long long u = t - N1 - N2;
      int k = (int)(u & 511);
      int n = (int)(u >> 9);
      cw3b[u] = f2bf(n < 50 ? cw3[(size_t)n * 512 + k] : 0.f);
    } else if (t < N1 + N2 + N3 + 128) {
      int u = (int)(t - N1 - N2 - N3);
      cb3p[u] = u < 50 ? cb3[u] : 0.f;
    }
  } else {
    int bq = bid - 18 - PREP_BLKS;
    int wid = bq * 4 + (tid >> 6);
    int lane = tid & 63;
    int b = wid >> 11, i = wid & 2047;
    const float* base = pts + (size_t)b * V0 * 3;
    float cx = base[i * 3], cy = base[i * 3 + 1], cz = base[i * 3 + 2];
    int cnt = 0, idx0 = 0;
    for (int j0 = 0; j0 < V0; j0 += 64) {
      int j = j0 + lane;
      float d2 = sqdist_f32(cx, cy, cz, base + (size_t)j * 3);
      bool in = (d2 <= 0.0625f);
      unsigned long long mask = __ballot(in);
      if (cnt == 0 && mask) idx0 = j0 + __builtin_ctzll(mask);
      if (in) {
        int rk = cnt + __popcll(mask & ((1ull << lane) - 1ull));
        if (rk < 32) ni1[(size_t)wid * 32 + rk] = j;
      }
      cnt += __popcll(mask);
      if (cnt >= 32) break;
    }
    for (int s = cnt + lane; s < 32; s += 64) ni1[(size_t)wid * 32 + s] = idx0;
  }
}

// ---------------------------------------------------------------------------
__device__ __forceinline__ void dirn(const float* base, int v, int nb,
                                     float& ox, float& oy, float& oz) {
  float dx = __fsub_rn(base[nb * 3 + 0], base[v * 3 + 0]);
  float dy = __fsub_rn(base[nb * 3 + 1], base[v * 3 + 1]);
  float dz = __fsub_rn(base[nb * 3 + 2], base[v * 3 + 2]);
  float s2 = __fadd_rn(__fadd_rn(__fmul_rn(dx, dx), __fmul_rn(dy, dy)),
                       __fmul_rn(dz, dz));
  float nrm = fmaxf(__fsqrt_rn(s2), 1e-12f);
  ox = __fdiv_rn(dx, nrm); oy = __fdiv_rn(dy, nrm); oz = __fdiv_rn(dz, nrm);
}

__device__ __forceinline__ void norm_col(const float* d, int k,
                                         float& ox, float& oy, float& oz) {
  float x = d[k], y = d[32 + k], z = d[64 + k];
  float s2 = __fadd_rn(__fadd_rn(__fmul_rn(x, x), __fmul_rn(y, y)),
                       __fmul_rn(z, z));
  float nrm = fmaxf(__fsqrt_rn(s2), 1e-12f);
  ox = __fdiv_rn(x, nrm); oy = __fdiv_rn(y, nrm); oz = __fdiv_rn(z, nrm);
}

// ---------------------------------------------------------------------------
// misc2: block 0 = perm compose; blocks [1,2049) = conv_surface (+linear1)
// ---------------------------------------------------------------------------
__global__ __launch_bounds__(256) void misc2_kernel(
    const int* __restrict__ rank, int* __restrict__ perm1,
    int* __restrict__ perm2, const float* __restrict__ pts,
    const int* __restrict__ ni, const float* __restrict__ d0,
    const float* __restrict__ w1, const float* __restrict__ b1,
    float* __restrict__ out, float* __restrict__ fn) {
  int bid = blockIdx.x, tid = threadIdx.x;
  if (bid == 0) {
    __shared__ int a1[2048];
    __shared__ int a2[2048];
    for (int i = tid; i < 2048; i += 256) a1[rank[i]] = i;
    __syncthreads();
    for (int i = tid; i < 2048; i += 256) a2[rank[2048 + i]] = a1[i];
    __syncthreads();
    for (int i = tid; i < 512; i += 256) perm1[i] = a2[i];
    for (int i = tid; i < 512; i += 256) a1[rank[4096 + i]] = i;
    __syncthreads();
    for (int i = tid; i < 128; i += 256) perm2[i] = a1[i];
    return;
  }
  __shared__ float sdir[3][32];
  __shared__ float sdn[8][32][3];
  __shared__ float sfm[8][32];
  if (tid < 32) {
    float x, y, z; norm_col(d0, tid, x, y, z);
    sdir[0][tid] = x; sdir[1][tid] = y; sdir[2][tid] = z;
  }
  int vloc = tid >> 5, k = tid & 31;
  size_t bvg = (size_t)(bid - 1) * 8 + vloc;
  int b = (int)(bvg >> 11), v = (int)(bvg & 2047);
  const float* base = pts + (size_t)b * V0 * 3;
  int nb = ni[bvg * 32 + k];
  float x, y, z; dirn(base, v, nb, x, y, z);
  sdn[vloc][k][0] = x; sdn[vloc][k][1] = y; sdn[vloc][k][2] = z;
  __syncthreads();
  float m = 0.f;
  for (int n = 0; n < 32; ++n) {
    float d = sdn[vloc][n][0] * sdir[0][k] + sdn[vloc][n][1] * sdir[1][k] +
              sdn[vloc][n][2] * sdir[2][k];
    m = fmaxf(m, fmaxf(d, 0.f));
  }
  out[bvg * 96 + k] = m;
  sfm[vloc][k] = m;
  __syncthreads();
  float a1v = b1[k], a2v = b1[k + 32];
  for (int c = 0; c < 32; ++c) {
    float vv = sfm[vloc][c];
    a1v += vv * w1[c * 64 + k];
    a2v += vv * w1[c * 64 + k + 32];
  }
  fn[bvg * 64 + k] = a1v;
  fn[bvg * 64 + k + 32] = a2v;
}

// ---------------------------------------------------------------------------
// conv_act (+ optional fused next-linear)
// ---------------------------------------------------------------------------
__global__ __launch_bounds__(256) void conv_act_kernel(
    const float* __restrict__ pts, const float* __restrict__ dd,
    const int* __restrict__ ni, const float* __restrict__ f,
    float* __restrict__ out, int Nv, int ldout, int colofs,
    const float* __restrict__ wn, const float* __restrict__ bn,
    float* __restrict__ fn) {
  __shared__ float sdir[3][32];
  __shared__ float sdn[8][32][3];
  __shared__ int sidx[8][32];
  __shared__ float sfm[8][256];
  int tid = threadIdx.x;
  if (tid < 32) {
    float x, y, z; norm_col(dd, tid, x, y, z);
    sdir[0][tid] = x; sdir[1][tid] = y; sdir[2][tid] = z;
  }
  int vloc = tid >> 5, k = tid & 31;
  size_t bvg = (size_t)blockIdx.x * 8 + vloc;
  int b = (int)(bvg / Nv), v = (int)(bvg % Nv);
  const float* base = pts + (size_t)b * Nv * 3;
  int nb = ni[bvg * 32 + k];
  float x, y, z; dirn(base, v, nb, x, y, z);
  sdn[vloc][k][0] = x; sdn[vloc][k][1] = y; sdn[vloc][k][2] = z;
  sidx[vloc][k] = nb;
  __syncthreads();
  float m = -INFINITY;
  size_t fb = (size_t)b * Nv * 64;
  for (int n = 0; n < 32; ++n) {
    float th = fmaxf(sdn[vloc][n][0] * sdir[0][k] + sdn[vloc][n][1] * sdir[1][k] +
                     sdn[vloc][n][2] * sdir[2][k], 0.f);
    float sup = f[fb + (size_t)sidx[vloc][n] * 64 + 32 + k];
    m = fmaxf(m, th * sup);
  }
  float center = f[bvg * 64 + k];
  float res = fmaxf(center + m, 0.f);
  out[bvg * ldout + colofs + k] = res;
  if (wn) {
    size_t rowbase = (size_t)blockIdx.x * 8;
#pragma unroll 1
    for (int r = 0; r < 8; ++r)
      if (tid < colofs) sfm[r][tid] = out[(rowbase + r) * ldout + tid];
    sfm[vloc][colofs + k] = res;
    __syncthreads();
    int cin = colofs + 32;
    float a1v = bn[k], a2v = bn[k + 32];
    for (int c = 0; c < cin; ++c) {
      float vv = sfm[vloc][c];
      a1v += vv * wn[c * 64 + k];
      a2v += vv * wn[c * 64 + k + 32];
    }
    fn[bvg * 64 + k] = a1v;
    fn[bvg * 64 + k + 32] = a2v;
  }
}

// ---------------------------------------------------------------------------
// conv_act_qbp: qbp fused in front of conv_act (+fused linear)
// ---------------------------------------------------------------------------
__global__ __launch_bounds__(256) void conv_act_qbp_kernel(
    const float* __restrict__ pts, int Nv, float rrq,
    const float* __restrict__ dd, int* __restrict__ ni_out,
    const float* __restrict__ f, float* __restrict__ out, int ldout,
    int colofs, const float* __restrict__ wn, const float* __restrict__ bn,
    float* __restrict__ fn) {
  __shared__ float spts[512 * 3];
  __shared__ float sdir[3][32];
  __shared__ float sdn[8][32][3];
  __shared__ int sni[8][32];
  __shared__ float sfm[8][256];
  int tid = threadIdx.x;
  int b = (blockIdx.x * 8) / Nv;
  int vbase = (blockIdx.x * 8) % Nv;
  const float* gp = pts + (size_t)b * Nv * 3;
  for (int i = tid; i < Nv * 3; i += 256) spts[i] = gp[i];
  if (tid < 32) {
    float x, y, z; norm_col(dd, tid, x, y, z);
    sdir[0][tid] = x; sdir[1][tid] = y; sdir[2][tid] = z;
  }
  __syncthreads();
  int lane = tid & 63, wv = tid >> 6;
  for (int rep = 0; rep < 2; ++rep) {
    int vl = wv * 2 + rep;
    int v = vbase + vl;
    float cx = spts[v * 3], cy = spts[v * 3 + 1], cz = spts[v * 3 + 2];
    int cnt = 0, idx0 = 0;
    for (int j0 = 0; j0 < Nv; j0 += 64) {
      int j = j0 + lane;
      float d2 = sqdist_f32(cx, cy, cz, spts + (size_t)j * 3);
      bool in = (d2 <= rrq);
      unsigned long long mask = __ballot(in);
      if (cnt == 0 && mask) idx0 = j0 + __builtin_ctzll(mask);
      if (in) {
        int rk = cnt + __popcll(mask & ((1ull << lane) - 1ull));
        if (rk < 32) sni[vl][rk] = j;
      }
      cnt += __popcll(mask);
      if (cnt >= 32) break;
    }
    for (int s = cnt + lane; s < 32; s += 64) sni[vl][s] = idx0;
  }
  __syncthreads();
  ni_out[(size_t)(blockIdx.x * 8) * 32 + tid] = sni[tid >> 5][tid & 31];
  int vloc = tid >> 5, k = tid & 31;
  size_t bvg = (size_t)blockIdx.x * 8 + vloc;
  int v = vbase + vloc;
  int nb = sni[vloc][k];
  float x, y, z; dirn(spts, v, nb, x, y, z);
  sdn[vloc][k][0] = x; sdn[vloc][k][1] = y; sdn[vloc][k][2] = z;
  __syncthreads();
  float m = -INFINITY;
  size_t fb = (size_t)b * Nv * 64;
  for (int n = 0; n < 32; ++n) {
    float th = fmaxf(sdn[vloc][n][0] * sdir[0][k] + sdn[vloc][n][1] * sdir[1][k] +
                     sdn[vloc][n][2] * sdir[2][k], 0.f);
    float sup = f[fb + (size_t)sni[vloc][n] * 64 + 32 + k];
    m = fmaxf(m, th * sup);
  }
  float center = f[bvg * 64 + k];
  float res = fmaxf(center + m, 0.f);
  out[bvg * ldout + colofs + k] = res;
  size_t rowbase = (size_t)blockIdx.x * 8;
#pragma unroll 1
  for (int r = 0; r < 8; ++r)
    if (tid < colofs) sfm[r][tid] = out[(rowbase + r) * ldout + tid];
  sfm[vloc][colofs + k] = res;
  __syncthreads();
  int cin = colofs + 32;
  float a1v = bn[k], a2v = bn[k + 32];
  for (int c = 0; c < cin; ++c) {
    float vv = sfm[vloc][c];
    a1v += vv * wn[c * 64 + k];
    a2v += vv * wn[c * 64 + k + 32];
  }
  fn[bvg * 64 + k] = a1v;
  fn[bvg * 64 + k + 32] = a2v;
}

// ---------------------------------------------------------------------------
// pool (+ fused next-linear)
// ---------------------------------------------------------------------------
__global__ __launch_bounds__(256) void pool_kernel(
    const float* __restrict__ pts_in, const float* __restrict__ fm_in,
    int ld_in, int C, int Nv_in, const int* __restrict__ perm, int Nv_out,
    float rr, float* __restrict__ pts_out, float* __restrict__ fm_out,
    int ld_out, const float* __restrict__ wn, const float* __restrict__ bn,
    float* __restrict__ fn) {
  __shared__ float spf[4][192];
  int wv = threadIdx.x >> 6;
  int lane = threadIdx.x & 63;
  int wid = blockIdx.x * 4 + wv;
  int b = wid / Nv_out, pp = wid - b * Nv_out;
  int v = perm[pp];
  const float* base = pts_in + (size_t)b * Nv_in * 3;
  float cx = base[v * 3], cy = base[v * 3 + 1], cz = base[v * 3 + 2];
  int nb[4]; int cnt = 0;
  for (int j0 = 0; j0 < Nv_in && cnt < 4; j0 += 64) {
    int j = j0 + lane;
    float d2 = sqdist_f32(cx, cy, cz, base + (size_t)j * 3);
    unsigned long long mask = __ballot(d2 <= rr);
    while (mask && cnt < 4) {
      int bp = __builtin_ctzll(mask);
      mask &= mask - 1;
      nb[cnt++] = j0 + bp;
    }
  }
  for (int q = cnt; q < 4; ++q) nb[q] = nb[0];
  if (lane < 3) pts_out[(size_t)wid * 3 + lane] = base[v * 3 + lane];
  size_t inrow = (size_t)b * Nv_in;
  size_t outrow = (size_t)wid * ld_out;
  for (int c = lane; c < C; c += 64) {
    float m = fm_in[(inrow + nb[0]) * ld_in + c];
    m = fmaxf(m, fm_in[(inrow + nb[1]) * ld_in + c]);
    m = fmaxf(m, fm_in[(inrow + nb[2]) * ld_in + c]);
    m = fmaxf(m, fm_in[(inrow + nb[3]) * ld_in + c]);
    fm_out[outrow + c] = m;
    spf[wv][c] = m;
  }
  __syncthreads();
  int o = threadIdx.x & 63, w_ = threadIdx.x >> 6;
  int wid0 = blockIdx.x * 4 + w_;
  float a = bn[o];
  for (int c = 0; c < C; ++c) a += spf[w_][c] * wn[c * 64 + o];
  fn[(size_t)wid0 * 64 + o] = a;
}

// ---------------------------------------------------------------------------
__global__ void gmax_kernel(const float* __restrict__ fm,
                            float* __restrict__ out) {
  int t = blockIdx.x * blockDim.x + threadIdx.x;
  if (t >= BS * 256) return;
  int b = t >> 8, c = t & 255;
  float m = -INFINITY;
  for (int v = 0; v < V2N; ++v)
    m = fmaxf(m, fm[((size_t)b * V2N + v) * 256 + c]);
  out[t] = m;
}

// ---------------------------------------------------------------------------
// fuse_row: inline argmin(n1,n2) + vectorized gather
// ---------------------------------------------------------------------------
__global__ __launch_bounds__(256) void fuse_row_kernel(
    const float* __restrict__ fm2, const float* __restrict__ fm5,
    const float* __restrict__ fm7, const float* __restrict__ fglob,
    const float* __restrict__ onehot, const float* __restrict__ verts,
    const float* __restrict__ v1, const float* __restrict__ v2,
    ushort_t* __restrict__ fuse_b) {
  __shared__ unsigned long long red[256];
  __shared__ int sn1, sn2;
  int bv = blockIdx.x;
  int b = bv >> 11;
  int tid = threadIdx.x;
  float cx = verts[(size_t)bv * 3 + 0];
  float cy = verts[(size_t)bv * 3 + 1];
  float cz = verts[(size_t)bv * 3 + 2];
  unsigned long long best = ~0ull;
  const float* sb = v1 + (size_t)b * V1N * 3;
  for (int j = tid; j < V1N; j += 256) {
    float d2 = sqdist_f32(cx, cy, cz, sb + (size_t)j * 3);
    unsigned long long key =
        (((unsigned long long)__float_as_uint(d2)) << 32) | (unsigned)j;
    best = best < key ? best : key;
  }
  red[tid] = best;
  __syncthreads();
  for (int s = 128; s > 0; s >>= 1) {
    if (tid < s) red[tid] = red[tid] < red[tid + s] ? red[tid] : red[tid + s];
    __syncthreads();
  }
  if (tid == 0) sn1 = (int)(red[0] & 0xffffffffu);
  __syncthreads();
  best = ~0ull;
  sb = v2 + (size_t)b * V2N * 3;
  for (int j = tid; j < V2N; j += 256) {
    float d2 = sqdist_f32(cx, cy, cz, sb + (size_t)j * 3);
    unsigned long long key =
        (((unsigned long long)__float_as_uint(d2)) << 32) | (unsigned)j;
    best = best < key ? best : key;
  }
  red[tid] = best;
  __syncthreads();
  for (int s = 128; s > 0; s >>= 1) {
    if (tid < s) red[tid] = red[tid] < red[tid + s] ? red[tid] : red[tid + s];
    __syncthreads();
  }
  if (tid == 0) sn2 = (int)(red[0] & 0xffffffffu);
  __syncthreads();
  const float* r2 = fm2 + (size_t)bv * 96;
  const float* r5 = fm5 + ((size_t)b * V1N + sn1) * 192;
  const float* r7 = fm7 + ((size_t)b * V2N + sn2) * 256;
  const float* rg = fglob + b * 256;
  const float* roh = onehot + b * 16;
  if (tid < KP1 / 8) {
    int c = tid * 8;
    const float* src = nullptr;
    if (c < 192) {
      int cc = (c < 32) ? c : (c < 96 ? c - 32 : c - 96);
      src = r2 + cc;
    } else if (c < 672) {
      int cc = (c < 320) ? c - 192 : (c < 480 ? c - 320 : c - 480);
      src = r5 + cc;
    } else if (c < 1152) {
      int cc = (c < 896) ? c - 672 : c - 896;
      src = r7 + cc;
    } else if (c < 1408) {
      src = rg + (c - 1152);
    } else if (c < 1424) {
      src = roh + (c - 1408);
    }
    float4 lo = make_float4(0.f, 0.f, 0.f, 0.f), hi = lo;
    if (src) { lo = *(const float4*)src; hi = *(const float4*)(src + 4); }
    bf16x8 o;
    o[0] = (short)f2bf(lo.x); o[1] = (short)f2bf(lo.y);
    o[2] = (short)f2bf(lo.z); o[3] = (short)f2bf(lo.w);
    o[4] = (short)f2bf(hi.x); o[5] = (short)f2bf(hi.y);
    o[6] = (short)f2bf(hi.z); o[7] = (short)f2bf(hi.w);
    *(bf16x8*)(fuse_b + (size_t)bv * KP1 + c) = o;
  }
}

// ---------------------------------------------------------------------------
// bf16 MFMA GEMM — BK=64 + XCD swizzle + XOR-8 chunk swizzle.
// LDS rows are 128 B (=32 banks): unswizzled, a quarter-wave's 16 rows all
// hit one 4-bank group (R10: conflicts 3×). Staging lane fetches global chunk
// (lane&7)^(lane>>3) of its row — 8-lane sub-group still covers the full
// 128 B row (coalescing + DMA lane*16B contract intact); readers use physical
// chunk (s*4+q)^(row&7) → 8 distinct chunks per 8 rows → 2 lanes/bank (free).
// R11 measured: SQ_LDS_BANK_CONFLICT = 0, gemm1 70 µs.
// ---------------------------------------------------------------------------
typedef const __attribute__((address_space(1))) unsigned int gas_u32;
typedef __attribute__((address_space(3))) unsigned int las_u32;

__global__ __launch_bounds__(256) void gemm_mfma_nt(
    const ushort_t* __restrict__ A, const ushort_t* __restrict__ B,
    const float* __restrict__ bias, ushort_t* __restrict__ Cb,
    float* __restrict__ Cf, int K, int ldc, int nvalid, int mode) {
  __shared__ ushort_t As[128 * 64];
  __shared__ ushort_t Bs[128 * 64];
  int tid = threadIdx.x;
  int lane = tid & 63, w = tid >> 6;
  int wm = (w >> 1) * 64, wn = (w & 1) * 64;
  int nb = gridDim.x;
  int flat = blockIdx.x + nb * blockIdx.y;
  int xcd = flat & 7, slot = flat >> 3;
  int nidx = slot % nb;
  int mband = xcd + 8 * (slot / nb);
  int bm = mband * 128, bn = nidx * 128;
  f32x4 acc[4][4];
#pragma unroll
  for (int i = 0; i < 4; ++i)
#pragma unroll
    for (int j = 0; j < 4; ++j) acc[i][j] = (f32x4){0.f, 0.f, 0.f, 0.f};

  // wave w stages rows [w*32, w*32+32) of A and B in 4 groups of 8 rows
  const ushort_t* gA[4];
  const ushort_t* gB[4];
  ushort_t* lA[4];
  ushort_t* lB[4];
  int rsub = lane >> 3;
  int scol = ((lane & 7) ^ rsub) * 8;        // XOR-8 swizzled global chunk
#pragma unroll
  for (int g = 0; g < 4; ++g) {
    int r = w * 32 + g * 8 + rsub;
    gA[g] = A + (size_t)(bm + r) * K + scol;
    gB[g] = B + (size_t)(bn + r) * K + scol;
    lA[g] = As + (w * 32 + g * 8) * 64;
    lB[g] = Bs + (w * 32 + g * 8) * 64;
  }
  int rA = lane & 15, q = lane >> 4;
  int r7 = rA & 7;

  for (int k0 = 0; k0 < K; k0 += 64) {
#pragma unroll
    for (int g = 0; g < 4; ++g)
      __builtin_amdgcn_global_load_lds((gas_u32*)(gA[g] + k0), (las_u32*)lA[g],
                                       16, 0, 0);
#pragma unroll
    for (int g = 0; g < 4; ++g)
      __builtin_amdgcn_global_load_lds((gas_u32*)(gB[g] + k0), (las_u32*)lB[g],
                                       16, 0, 0);
    __syncthreads();
#pragma unroll
    for (int s = 0; s < 2; ++s) {
      int pc = ((s * 4 + q) ^ r7) * 8;        // physical chunk offset
      bf16x8 af[4], bfr[4];
#pragma unroll
      for (int i = 0; i < 4; ++i)
        af[i] = *(const bf16x8*)(As + (wm + i * 16 + rA) * 64 + pc);
#pragma unroll
      for (int j = 0; j < 4; ++j)
        bfr[j] = *(const bf16x8*)(Bs + (wn + j * 16 + rA) * 64 + pc);
#pragma unroll
      for (int i = 0; i < 4; ++i)
#pragma unroll
        for (int j = 0; j < 4; ++j)
          acc[i][j] = __builtin_amdgcn_mfma_f32_16x16x32_bf16(af[i], bfr[j],
                                                              acc[i][j], 0, 0, 0);
    }
    __syncthreads();
  }

  int rowq = (lane >> 4) * 4;
  int coll = lane & 15;
#pragma unroll
  for (int i = 0; i < 4; ++i) {
#pragma unroll
    for (int j = 0; j < 4; ++j) {
      int col = bn + wn + j * 16 + coll;
      float bi = bias[col];
#pragma unroll
      for (int r = 0; r < 4; ++r) {
        int row = bm + wm + i * 16 + rowq + r;
        float v = acc[i][j][r] + bi;
        if (mode == 0) {
          Cb[(size_t)row * ldc + col] = f2bf(fmaxf(v, 0.f));
        } else if (col < nvalid) {
          Cf[(size_t)row * ldc + col] = v;
        }
      }
    }
  }
}

// ---------------------------------------------------------------------------
extern "C" void kernel_launch(void* const* d_in, const int* in_sizes, int n_in,
                              void* d_out, int out_size, void* d_ws,
                              size_t ws_size, hipStream_t stream) {
  const float* vertices = (const float*)d_in[0];
  const float* onehot = (const float*)d_in[1];
  const float* d0 = (const float*)d_in[2];
  const float *w[8], *bb[8], *dd[8];
  for (int i = 1; i <= 7; ++i) {
    w[i] = (const float*)d_in[3 * i];
    bb[i] = (const float*)d_in[3 * i + 1];
    dd[i] = (const float*)d_in[3 * i + 2];
  }
  const float* cw1 = (const float*)d_in[24];
  const float* cb1 = (const float*)d_in[25];
  const float* cw2 = (const float*)d_in[26];
  const float* cb2 = (const float*)d_in[27];
  const float* cw3 = (const float*)d_in[28];
  const float* cb3 = (const float*)d_in[29];
  float* out = (float*)d_out;

  char* wsp = (char*)d_ws;
  size_t off = 0;
  auto alloc = [&](size_t bytes) -> void* {
    void* p = wsp + off;
    off += (bytes + 255) & ~(size_t)255;
    return p;
  };
  const int M = BS * V0;  // 16384
  int* rank = (int*)alloc(4608 * 4);
  int* perm1 = (int*)alloc(512 * 4);
  int* perm2 = (int*)alloc(128 * 4);
  int* ni1 = (int*)alloc((size_t)BS * V0 * 32 * 4);
  int* ni2 = (int*)alloc((size_t)BS * V1N * 32 * 4);
  int* ni3 = (int*)alloc((size_t)BS * V2N * 32 * 4);
  float* fm2buf = (float*)alloc((size_t)BS * V0 * 96 * 4);
  float* fm5buf = (float*)alloc((size_t)BS * V1N * 192 * 4);
  float* fm7buf = (float*)alloc((size_t)BS * V2N * 256 * 4);
  float* fbuf = (float*)alloc((size_t)BS * V0 * 64 * 4);
  float* v1 = (float*)alloc((size_t)BS * V1N * 3 * 4);
  float* v2 = (float*)alloc((size_t)BS * V2N * 3 * 4);
  float* fglob = (float*)alloc((size_t)BS * 256 * 4);
  ushort_t* fuse_b = (ushort_t*)alloc((size_t)M * KP1 * 2);
  ushort_t* h1b = (ushort_t*)alloc((size_t)M * 1024 * 2);
  ushort_t* h2b = (ushort_t*)alloc((size_t)M * 512 * 2);
  ushort_t* cw1b = (ushort_t*)alloc((size_t)1024 * KP1 * 2);
  ushort_t* cw2b = (ushort_t*)alloc((size_t)512 * 1024 * 2);
  ushort_t* cw3b = (ushort_t*)alloc((size_t)128 * 512 * 2);
  float* cb3p = (float*)alloc(128 * 4);

  float rr1 = 0.0625f;
  float rr2 = (float)(0.39 * 0.39);
  float rr3 = (float)(0.63 * 0.63);

  // 1: rank + weight-prep + qbp1
  misc1_kernel<<<18 + PREP_BLKS + 4096, 256, 0, stream>>>(
      rank, cw1, cw2, cw3, cb3, cw1b, cw2b, cw3b, cb3p, vertices, ni1);
  // 2: perm compose + conv_surface(+linear1)
  misc2_kernel<<<1 + BS * V0 / 8, 256, 0, stream>>>(
      rank, perm1, perm2, vertices, ni1, d0, w[1], bb[1], fm2buf, fbuf);
  // 3-4: level-1 convs
  conv_act_kernel<<<BS * V0 / 8, 256, 0, stream>>>(
      vertices, dd[1], ni1, fbuf, fm2buf, V0, 96, 32, w[2], bb[2], fbuf);
  conv_act_kernel<<<BS * V0 / 8, 256, 0, stream>>>(
      vertices, dd[2], ni1, fbuf, fm2buf, V0, 96, 64, nullptr, nullptr, nullptr);
  // 5: pool1 (+linear3)
  pool_kernel<<<BS * V1N / 4, 256, 0, stream>>>(
      vertices, fm2buf, 96, 96, V0, perm1, V1N, rr1, v1, fm5buf, 192,
      w[3], bb[3], fbuf);
  // 6-8: level-2 convs (first fuses qbp2 + linear4)
  conv_act_qbp_kernel<<<BS * V1N / 8, 256, 0, stream>>>(
      v1, V1N, rr2, dd[3], ni2, fbuf, fm5buf, 192, 96, w[4], bb[4], fbuf);
  conv_act_kernel<<<BS * V1N / 8, 256, 0, stream>>>(
      v1, dd[4], ni2, fbuf, fm5buf, V1N, 192, 128, w[5], bb[5], fbuf);
  conv_act_kernel<<<BS * V1N / 8, 256, 0, stream>>>(
      v1, dd[5], ni2, fbuf, fm5buf, V1N, 192, 160, nullptr, nullptr, nullptr);
  // 9: pool2 (+linear6)
  pool_kernel<<<BS * V2N / 4, 256, 0, stream>>>(
      v1, fm5buf, 192, 192, V1N, perm2, V2N, rr2, v2, fm7buf, 256,
      w[6], bb[6], fbuf);
  // 10-11: level-3 convs (first fuses qbp3 + linear7)
  conv_act_qbp_kernel<<<BS * V2N / 8, 256, 0, stream>>>(
      v2, V2N, rr3, dd[6], ni3, fbuf, fm7buf, 256, 192, w[7], bb[7], fbuf);
  conv_act_kernel<<<BS * V2N / 8, 256, 0, stream>>>(
      v2, dd[7], ni3, fbuf, fm7buf, V2N, 256, 224, nullptr, nullptr, nullptr);
  // 12: global max
  gmax_kernel<<<BS, 256, 0, stream>>>(fm7buf, fglob);
  // 13: fused nearest + gather + bf16 cast
  fuse_row_kernel<<<M, 256, 0, stream>>>(fm2buf, fm5buf, fm7buf, fglob, onehot,
                                         vertices, v1, v2, fuse_b);
  // 14-16: MLP head (bf16 MFMA, BK=64 + XOR-8 swizzle)
  gemm_mfma_nt<<<dim3(1024 / 128, M / 128), 256, 0, stream>>>(
      fuse_b, cw1b, cb1, h1b, nullptr, KP1, 1024, 1024, 0);
  gemm_mfma_nt<<<dim3(512 / 128, M / 128), 256, 0, stream>>>(
      h1b, cw2b, cb2, h2b, nullptr, 1024, 512, 512, 0);
  gemm_mfma_nt<<<dim3(1, M / 128), 256, 0, stream>>>(
      h2b, cw3b, cb3p, nullptr, out, 512, 50, 50, 1);
}